// Round 1
// baseline (36584.616 us; speedup 1.0000x reference)
//
#include <hip/hip_runtime.h>
#include <hip/hip_bf16.h>

#define DD 512
#define LL 512
#define BB 64
#define NT 1536
#define MROWS (LL*BB)

static __device__ __forceinline__ unsigned short f2bf(float f) {
  unsigned int u = __float_as_uint(f);
  unsigned int r = (u + 0x7fffu + ((u >> 16) & 1u)) >> 16;
  return (unsigned short)r;
}
static __device__ __forceinline__ float bf2f(unsigned short s) {
  return __uint_as_float(((unsigned int)s) << 16);
}

__global__ void cvt_bf16_k(const float* __restrict__ in, unsigned short* __restrict__ out, int n) {
  int i = blockIdx.x * 256 + threadIdx.x;
  if (i < n) out[i] = f2bf(in[i]);
}

// x[row, :] = emb[xs[row], :], float4-vectorized
__global__ void gather_k(const int* __restrict__ xs, const float* __restrict__ emb,
                         float* __restrict__ x) {
  int i = blockIdx.x * 256 + threadIdx.x;   // float4 index; total MROWS*128 exact
  int row = i >> 7;
  int col = i & 127;
  const float4* src = (const float4*)(emb + (size_t)xs[row] * DD);
  ((float4*)(x + (size_t)row * DD))[col] = src[col];
}

// C[M,1536](bf16) = A[M,512] @ W[512,1536] + bias ; fp32 compute
// 128x128 tile, BK=16, 256 threads, 8x8 micro-tile
__global__ __launch_bounds__(256)
void gemm_k(const float* __restrict__ A, const float* __restrict__ W,
            const float* __restrict__ bias, unsigned short* __restrict__ C) {
  __shared__ float As[16][128];
  __shared__ float Bs[16][128];
  const int tid = threadIdx.x;
  const int tx = tid & 15;
  const int ty = tid >> 4;
  const int m0 = blockIdx.y * 128;
  const int n0 = blockIdx.x * 128;
  const int lm = tid >> 1;
  const int lk = (tid & 1) * 8;
  const int wk = tid >> 4;
  const int wn = (tid & 15) * 8;
  float acc[8][8];
#pragma unroll
  for (int i = 0; i < 8; ++i)
#pragma unroll
    for (int j = 0; j < 8; ++j) acc[i][j] = 0.f;

  for (int k0 = 0; k0 < DD; k0 += 16) {
    float4 a0 = *(const float4*)(A + (size_t)(m0 + lm) * DD + k0 + lk);
    float4 a1 = *(const float4*)(A + (size_t)(m0 + lm) * DD + k0 + lk + 4);
    float4 w0 = *(const float4*)(W + (size_t)(k0 + wk) * NT + n0 + wn);
    float4 w1 = *(const float4*)(W + (size_t)(k0 + wk) * NT + n0 + wn + 4);
    __syncthreads();
    As[lk + 0][lm] = a0.x; As[lk + 1][lm] = a0.y; As[lk + 2][lm] = a0.z; As[lk + 3][lm] = a0.w;
    As[lk + 4][lm] = a1.x; As[lk + 5][lm] = a1.y; As[lk + 6][lm] = a1.z; As[lk + 7][lm] = a1.w;
    *(float4*)&Bs[wk][wn] = w0;
    *(float4*)&Bs[wk][wn + 4] = w1;
    __syncthreads();
#pragma unroll
    for (int kk = 0; kk < 16; ++kk) {
      float a[8], w[8];
      *(float4*)&a[0] = *(const float4*)&As[kk][ty * 8];
      *(float4*)&a[4] = *(const float4*)&As[kk][ty * 8 + 4];
      *(float4*)&w[0] = *(const float4*)&Bs[kk][tx * 8];
      *(float4*)&w[4] = *(const float4*)&Bs[kk][tx * 8 + 4];
#pragma unroll
      for (int i = 0; i < 8; ++i)
#pragma unroll
        for (int j = 0; j < 8; ++j)
          acc[i][j] = fmaf(a[i], w[j], acc[i][j]);
    }
  }
#pragma unroll
  for (int i = 0; i < 8; ++i) {
    size_t rb = (size_t)(m0 + ty * 8 + i) * NT + n0 + tx * 8;
#pragma unroll
    for (int jv = 0; jv < 2; ++jv) {
      ushort4 v;
      v.x = f2bf(acc[i][jv*4+0] + bias[n0 + tx*8 + jv*4 + 0]);
      v.y = f2bf(acc[i][jv*4+1] + bias[n0 + tx*8 + jv*4 + 1]);
      v.z = f2bf(acc[i][jv*4+2] + bias[n0 + tx*8 + jv*4 + 2]);
      v.w = f2bf(acc[i][jv*4+3] + bias[n0 + tx*8 + jv*4 + 3]);
      *(ushort4*)(C + rb + jv*4) = v;
    }
  }
}

// One block per batch element; c[512] in LDS; 512 steps sequential.
// gx: [L,B,1536] bf16, Wcb: [512,1024] bf16, xin/hout: [L,B,512] f32
__global__ __launch_bounds__(512)
void scan_k(const unsigned short* __restrict__ gx,
            const unsigned short* __restrict__ Wcb,
            const float* __restrict__ xin,
            float* __restrict__ hout,
            float* __restrict__ cbuf,
            int reverse) {
  __shared__ float c_sh[DD];
  __shared__ float gi_sh[DD];
  __shared__ float gf_sh[DD];
  const int b = blockIdx.x;
  const int tid = threadIdx.x;
  c_sh[tid] = cbuf[b * DD + tid];
  __syncthreads();
  const unsigned int* wp = (const unsigned int*)Wcb + tid;  // 2 bf16 per uint; 512 uints/row
  for (int s = 0; s < LL; ++s) {
    const int t = reverse ? (LL - 1 - s) : s;
    float a0 = 0.f, a1 = 0.f;
#pragma unroll 8
    for (int d = 0; d < DD; ++d) {
      float cd = c_sh[d];
      unsigned int w = wp[(size_t)d * 512];
      a0 = fmaf(cd, __uint_as_float(w << 16), a0);
      a1 = fmaf(cd, __uint_as_float(w & 0xffff0000u), a1);
    }
    if (tid < 256) { gi_sh[2*tid] = a0; gi_sh[2*tid+1] = a1; }
    else { int u = 2*tid - 512; gf_sh[u] = a0; gf_sh[u+1] = a1; }
    __syncthreads();
    const size_t gbase = ((size_t)t * BB + b) * NT;
    const size_t xbase = ((size_t)t * BB + b) * DD;
    float gi = bf2f(gx[gbase + tid]);
    float gf = bf2f(gx[gbase + DD + tid]);
    float gc = bf2f(gx[gbase + 2*DD + tid]);
    float iv = 1.f / (1.f + __expf(-(gi + gi_sh[tid])));
    float fv = 1.f / (1.f + __expf(-(gf + gf_sh[tid])));
    float cn = fmaf(fv, c_sh[tid], iv * gc);
    hout[xbase + tid] = tanhf(cn) + xin[xbase + tid];
    c_sh[tid] = cn;
    __syncthreads();
  }
  cbuf[b * DD + tid] = c_sh[tid];
}

extern "C" void kernel_launch(void* const* d_in, const int* in_sizes, int n_in,
                              void* d_out, int out_size, void* d_ws, size_t ws_size,
                              hipStream_t stream) {
  const int* xs = (const int*)d_in[0];
  const float* emb = (const float*)d_in[1];
  const float* Wx = (const float*)d_in[2];
  const float* Wc = (const float*)d_in[3];
  const float* bias = (const float*)d_in[4];
  float* out = (float*)d_out;
  char* ws = (char*)d_ws;

  // workspace layout
  unsigned short* gx = (unsigned short*)ws;                          // 96 MiB: L*B*1536 bf16
  float* xB = (float*)(ws + (size_t)100663296);                      // 64 MiB: L*B*512 f32
  unsigned short* Wcb = (unsigned short*)(ws + (size_t)167772160);   // 4 MiB: 4*512*1024 bf16
  float* cbuf = (float*)(ws + (size_t)171966464);                    // 128 KiB: B*512 f32

  hipMemsetAsync(cbuf, 0, (size_t)BB * DD * sizeof(float), stream);
  {
    int n = 4 * 512 * 1024;
    cvt_bf16_k<<<(n + 255) / 256, 256, 0, stream>>>(Wc, Wcb, n);
  }
  gather_k<<<MROWS * 128 / 256, 256, 0, stream>>>(xs, emb, out);

  for (int s = 0; s < 4; ++s) {
    const float* xin = (s % 2 == 0) ? out : xB;
    float* xout = (s % 2 == 0) ? xB : out;
    gemm_k<<<dim3(NT / 128, MROWS / 128), 256, 0, stream>>>(
        xin, Wx + (size_t)s * DD * NT, bias + (size_t)s * NT, gx);
    scan_k<<<BB, 512, 0, stream>>>(
        gx, Wcb + (size_t)s * DD * 1024, xin, xout, cbuf, s & 1);
  }
}

// Round 3
// 20022.067 us; speedup vs baseline: 1.8272x; 1.8272x over previous
//
#include <hip/hip_runtime.h>
#include <hip/hip_bf16.h>

#define DD 512
#define LL 512
#define BB 64
#define NT 1536
#define MROWS (LL*BB)

static __device__ __forceinline__ unsigned short f2bf(float f) {
  unsigned int u = __float_as_uint(f);
  unsigned int r = (u + 0x7fffu + ((u >> 16) & 1u)) >> 16;
  return (unsigned short)r;
}
static __device__ __forceinline__ float bf2f(unsigned short s) {
  return __uint_as_float(((unsigned int)s) << 16);
}
// D.f32 += S0.bf16[0]*S1.bf16[0] + S0.bf16[1]*S1.bf16[1]
static __device__ __forceinline__ float dot2bf(unsigned int w, unsigned int c, float acc) {
  asm("v_dot2_f32_bf16 %0, %1, %2, %0" : "+v"(acc) : "v"(w), "v"(c));
  return acc;
}

// Repack Wc[s][512 d][1024 col] f32 -> Wp per scan, bf16-pair, kk-major coalesced:
// per scan (2^18 uints): plane(i/f) 2^17 | kk(0..63)*2048 | t(0..511)*4 | q(0..3)
// uint = ( bf16(Wc[8kk+2q][col]) , bf16(Wc[8kk+2q+1][col]) ), col = t + 512*plane
__global__ void pack_wc_k(const float* __restrict__ Wc, unsigned int* __restrict__ Wp) {
  int u = blockIdx.x * 256 + threadIdx.x;      // 4*2^18 total
  int s = u >> 18;
  int r = u & 0x3ffff;
  int plane = r >> 17;
  int r2 = r & 0x1ffff;
  int kk = r2 >> 11;
  int rem = r2 & 0x7ff;
  int t = rem >> 2;
  int q = rem & 3;
  int k = kk * 4 + q;
  int col = t + (plane << 9);
  size_t base = (size_t)s * DD * 1024;
  float lo = Wc[base + (size_t)(2 * k) * 1024 + col];
  float hi = Wc[base + (size_t)(2 * k + 1) * 1024 + col];
  Wp[u] = (unsigned int)f2bf(lo) | ((unsigned int)f2bf(hi) << 16);
}

// x[row, :] = emb[xs[row], :], float4-vectorized
__global__ void gather_k(const int* __restrict__ xs, const float* __restrict__ emb,
                         float* __restrict__ x) {
  int i = blockIdx.x * 256 + threadIdx.x;
  int row = i >> 7;
  int col = i & 127;
  const float4* src = (const float4*)(emb + (size_t)xs[row] * DD);
  ((float4*)(x + (size_t)row * DD))[col] = src[col];
}

// C[M,1536](bf16) = A[M,512] @ W[512,1536] + bias ; fp32 compute
__global__ __launch_bounds__(256)
void gemm_k(const float* __restrict__ A, const float* __restrict__ W,
            const float* __restrict__ bias, unsigned short* __restrict__ C) {
  __shared__ float As[16][128];
  __shared__ float Bs[16][128];
  const int tid = threadIdx.x;
  const int tx = tid & 15;
  const int ty = tid >> 4;
  const int m0 = blockIdx.y * 128;
  const int n0 = blockIdx.x * 128;
  const int lm = tid >> 1;
  const int lk = (tid & 1) * 8;
  const int wk = tid >> 4;
  const int wn = (tid & 15) * 8;
  float acc[8][8];
#pragma unroll
  for (int i = 0; i < 8; ++i)
#pragma unroll
    for (int j = 0; j < 8; ++j) acc[i][j] = 0.f;

  for (int k0 = 0; k0 < DD; k0 += 16) {
    float4 a0 = *(const float4*)(A + (size_t)(m0 + lm) * DD + k0 + lk);
    float4 a1 = *(const float4*)(A + (size_t)(m0 + lm) * DD + k0 + lk + 4);
    float4 w0 = *(const float4*)(W + (size_t)(k0 + wk) * NT + n0 + wn);
    float4 w1 = *(const float4*)(W + (size_t)(k0 + wk) * NT + n0 + wn + 4);
    __syncthreads();
    As[lk + 0][lm] = a0.x; As[lk + 1][lm] = a0.y; As[lk + 2][lm] = a0.z; As[lk + 3][lm] = a0.w;
    As[lk + 4][lm] = a1.x; As[lk + 5][lm] = a1.y; As[lk + 6][lm] = a1.z; As[lk + 7][lm] = a1.w;
    *(float4*)&Bs[wk][wn] = w0;
    *(float4*)&Bs[wk][wn + 4] = w1;
    __syncthreads();
#pragma unroll
    for (int kk = 0; kk < 16; ++kk) {
      float a[8], w[8];
      *(float4*)&a[0] = *(const float4*)&As[kk][ty * 8];
      *(float4*)&a[4] = *(const float4*)&As[kk][ty * 8 + 4];
      *(float4*)&w[0] = *(const float4*)&Bs[kk][tx * 8];
      *(float4*)&w[4] = *(const float4*)&Bs[kk][tx * 8 + 4];
#pragma unroll
      for (int i = 0; i < 8; ++i)
#pragma unroll
        for (int j = 0; j < 8; ++j)
          acc[i][j] = fmaf(a[i], w[j], acc[i][j]);
    }
  }
#pragma unroll
  for (int i = 0; i < 8; ++i) {
    size_t rb = (size_t)(m0 + ty * 8 + i) * NT + n0 + tx * 8;
#pragma unroll
    for (int jv = 0; jv < 2; ++jv) {
      ushort4 v;
      v.x = f2bf(acc[i][jv*4+0] + bias[n0 + tx*8 + jv*4 + 0]);
      v.y = f2bf(acc[i][jv*4+1] + bias[n0 + tx*8 + jv*4 + 1]);
      v.z = f2bf(acc[i][jv*4+2] + bias[n0 + tx*8 + jv*4 + 2]);
      v.w = f2bf(acc[i][jv*4+3] + bias[n0 + tx*8 + jv*4 + 3]);
      *(ushort4*)(C + rb + jv*4) = v;
    }
  }
}

// One block per batch element; thread t owns output columns t (i) and 512+t (f).
// c kept in a register; bf16-packed c broadcast via LDS; weights via dot2.
__global__ __launch_bounds__(512, 2)
void scan_k(const unsigned short* __restrict__ gx,
            const uint4* __restrict__ Wp,     // per-scan base, uint4 units
            const float* __restrict__ xin,
            float* __restrict__ hout,
            float* __restrict__ cbuf,
            int reverse) {
  __shared__ unsigned short cs[DD];
  const int b = blockIdx.x;
  const int tid = threadIdx.x;
  float c_reg = cbuf[b * DD + tid];
  cs[tid] = f2bf(c_reg);
  __syncthreads();
  const uint4* w0p = Wp + tid;             // + kk*512
  const uint4* w1p = Wp + 32768 + tid;     // f-plane (131072 uints)
  const uint4* cv = (const uint4*)cs;      // 64 entries, broadcast reads
  for (int s = 0; s < LL; ++s) {
    const int t = reverse ? (LL - 1 - s) : s;
    const size_t gbase = ((size_t)t * BB + b) * NT;
    const size_t xbase = ((size_t)t * BB + b) * DD;
    // issue the stream loads early; matvec hides their latency
    float gi = bf2f(gx[gbase + tid]);
    float gf = bf2f(gx[gbase + DD + tid]);
    float gc = bf2f(gx[gbase + 2 * DD + tid]);
    float xv = xin[xbase + tid];
    float a0 = 0.f, a1 = 0.f;
#pragma unroll 8
    for (int kk = 0; kk < 64; ++kk) {
      uint4 wa = w0p[(size_t)kk * 512];
      uint4 wb = w1p[(size_t)kk * 512];
      uint4 cp = cv[kk];
      a0 = dot2bf(wa.x, cp.x, a0); a0 = dot2bf(wa.y, cp.y, a0);
      a0 = dot2bf(wa.z, cp.z, a0); a0 = dot2bf(wa.w, cp.w, a0);
      a1 = dot2bf(wb.x, cp.x, a1); a1 = dot2bf(wb.y, cp.y, a1);
      a1 = dot2bf(wb.z, cp.z, a1); a1 = dot2bf(wb.w, cp.w, a1);
    }
    float iv = 1.f / (1.f + __expf(-(gi + a0)));
    float fv = 1.f / (1.f + __expf(-(gf + a1)));
    float cn = fmaf(fv, c_reg, iv * gc);
    hout[xbase + tid] = tanhf(cn) + xv;
    c_reg = cn;
    __syncthreads();              // all matvec reads of cs complete
    cs[tid] = f2bf(cn);
    __syncthreads();              // new c visible
  }
  cbuf[b * DD + tid] = c_reg;
}

extern "C" void kernel_launch(void* const* d_in, const int* in_sizes, int n_in,
                              void* d_out, int out_size, void* d_ws, size_t ws_size,
                              hipStream_t stream) {
  const int* xs = (const int*)d_in[0];
  const float* emb = (const float*)d_in[1];
  const float* Wx = (const float*)d_in[2];
  const float* Wc = (const float*)d_in[3];
  const float* bias = (const float*)d_in[4];
  float* out = (float*)d_out;
  char* ws = (char*)d_ws;

  unsigned short* gx = (unsigned short*)ws;                          // 96 MiB
  float* xB = (float*)(ws + (size_t)100663296);                      // 64 MiB
  unsigned int* Wp = (unsigned int*)(ws + (size_t)167772160);        // 4 MiB
  float* cbuf = (float*)(ws + (size_t)171966464);                    // 128 KiB

  hipMemsetAsync(cbuf, 0, (size_t)BB * DD * sizeof(float), stream);
  pack_wc_k<<<4096, 256, 0, stream>>>(Wc, Wp);
  gather_k<<<MROWS * 128 / 256, 256, 0, stream>>>(xs, emb, out);

  for (int s = 0; s < 4; ++s) {
    const float* xin = (s % 2 == 0) ? out : xB;
    float* xout = (s % 2 == 0) ? xB : out;
    gemm_k<<<dim3(NT / 128, MROWS / 128), 256, 0, stream>>>(
        xin, Wx + (size_t)s * DD * NT, bias + (size_t)s * NT, gx);
    scan_k<<<BB, 512, 0, stream>>>(
        gx, (const uint4*)(Wp + (size_t)s * 262144), xin, xout, cbuf, s & 1);
  }
}

// Round 4
// 16017.389 us; speedup vs baseline: 2.2841x; 1.2500x over previous
//
#include <hip/hip_runtime.h>
#include <hip/hip_bf16.h>

#define DD 512
#define LL 512
#define BB 64
#define NT 1536
#define MROWS (LL*BB)

static __device__ __forceinline__ unsigned short f2bf(float f) {
  unsigned int u = __float_as_uint(f);
  unsigned int r = (u + 0x7fffu + ((u >> 16) & 1u)) >> 16;
  return (unsigned short)r;
}
static __device__ __forceinline__ float bf2f(unsigned short s) {
  return __uint_as_float(((unsigned int)s) << 16);
}
// D.f32 += S0.bf16[0]*S1.bf16[0] + S0.bf16[1]*S1.bf16[1]
static __device__ __forceinline__ float dot2bf(unsigned int w, unsigned int c, float acc) {
  asm("v_dot2_f32_bf16 %0, %1, %2, %0" : "+v"(acc) : "v"(w), "v"(c));
  return acc;
}

// Repack Wc[s][512 d][1024 col] f32 -> Wp, per (scan,dim-group) 128 KiB slices:
// uint4-flat index = (s*8+dg)*8192 + kk*128 + pl*64 + j ; quad q holds d = kk*8+2q, +1
// col = pl*512 + dg*64 + j
__global__ void pack_wc_k(const float* __restrict__ Wc, unsigned int* __restrict__ Wp) {
  int u = blockIdx.x * 256 + threadIdx.x;      // 4*8*32768 = 1048576 total
  int s8dg = u >> 15;
  int s = s8dg >> 3, dg = s8dg & 7;
  int r2 = u & 32767;
  int q = r2 & 3;
  int t3 = r2 >> 2;
  int jj = t3 & 63;
  int pl = (t3 >> 6) & 1;
  int kk = t3 >> 7;
  int d0 = kk * 8 + 2 * q;
  int col = pl * 512 + dg * 64 + jj;
  size_t base = (size_t)s * DD * 1024;
  float lo = Wc[base + (size_t)d0 * 1024 + col];
  float hi = Wc[base + (size_t)(d0 + 1) * 1024 + col];
  Wp[u] = (unsigned int)f2bf(lo) | ((unsigned int)f2bf(hi) << 16);
}

// x[row, :] = emb[xs[row], :], float4-vectorized
__global__ void gather_k(const int* __restrict__ xs, const float* __restrict__ emb,
                         float* __restrict__ x) {
  int i = blockIdx.x * 256 + threadIdx.x;
  int row = i >> 7;
  int col = i & 127;
  const float4* src = (const float4*)(emb + (size_t)xs[row] * DD);
  ((float4*)(x + (size_t)row * DD))[col] = src[col];
}

// C[M,1536](bf16) = A[M,512] @ W[512,1536] + bias ; fp32 compute
__global__ __launch_bounds__(256)
void gemm_k(const float* __restrict__ A, const float* __restrict__ W,
            const float* __restrict__ bias, unsigned short* __restrict__ C) {
  __shared__ float As[16][128];
  __shared__ float Bs[16][128];
  const int tid = threadIdx.x;
  const int tx = tid & 15;
  const int ty = tid >> 4;
  const int m0 = blockIdx.y * 128;
  const int n0 = blockIdx.x * 128;
  const int lm = tid >> 1;
  const int lk = (tid & 1) * 8;
  const int wk = tid >> 4;
  const int wn = (tid & 15) * 8;
  float acc[8][8];
#pragma unroll
  for (int i = 0; i < 8; ++i)
#pragma unroll
    for (int j = 0; j < 8; ++j) acc[i][j] = 0.f;

  for (int k0 = 0; k0 < DD; k0 += 16) {
    float4 a0 = *(const float4*)(A + (size_t)(m0 + lm) * DD + k0 + lk);
    float4 a1 = *(const float4*)(A + (size_t)(m0 + lm) * DD + k0 + lk + 4);
    float4 w0 = *(const float4*)(W + (size_t)(k0 + wk) * NT + n0 + wn);
    float4 w1 = *(const float4*)(W + (size_t)(k0 + wk) * NT + n0 + wn + 4);
    __syncthreads();
    As[lk + 0][lm] = a0.x; As[lk + 1][lm] = a0.y; As[lk + 2][lm] = a0.z; As[lk + 3][lm] = a0.w;
    As[lk + 4][lm] = a1.x; As[lk + 5][lm] = a1.y; As[lk + 6][lm] = a1.z; As[lk + 7][lm] = a1.w;
    *(float4*)&Bs[wk][wn] = w0;
    *(float4*)&Bs[wk][wn + 4] = w1;
    __syncthreads();
#pragma unroll
    for (int kk = 0; kk < 16; ++kk) {
      float a[8], w[8];
      *(float4*)&a[0] = *(const float4*)&As[kk][ty * 8];
      *(float4*)&a[4] = *(const float4*)&As[kk][ty * 8 + 4];
      *(float4*)&w[0] = *(const float4*)&Bs[kk][tx * 8];
      *(float4*)&w[4] = *(const float4*)&Bs[kk][tx * 8 + 4];
#pragma unroll
      for (int i = 0; i < 8; ++i)
#pragma unroll
        for (int j = 0; j < 8; ++j)
          acc[i][j] = fmaf(a[i], w[j], acc[i][j]);
    }
  }
#pragma unroll
  for (int i = 0; i < 8; ++i) {
    size_t rb = (size_t)(m0 + ty * 8 + i) * NT + n0 + tx * 8;
#pragma unroll
    for (int jv = 0; jv < 2; ++jv) {
      ushort4 v;
      v.x = f2bf(acc[i][jv*4+0] + bias[n0 + tx*8 + jv*4 + 0]);
      v.y = f2bf(acc[i][jv*4+1] + bias[n0 + tx*8 + jv*4 + 1]);
      v.z = f2bf(acc[i][jv*4+2] + bias[n0 + tx*8 + jv*4 + 2]);
      v.w = f2bf(acc[i][jv*4+3] + bias[n0 + tx*8 + jv*4 + 3]);
      *(ushort4*)(C + rb + jv*4) = v;
    }
  }
}

// 64 blocks = 8 batch-groups (bg=blockIdx%8, so partners share an XCD under
// round-robin dispatch) x 8 dim-groups. Block owns 8 batches x 64 c-dims.
// Weights (128 KiB slice) LDS-resident; full c exchanged per step via
// device-scope counter + L2-bypassing loads.
__global__ __launch_bounds__(512, 1)
void scan_k(const unsigned short* __restrict__ gx,
            const uint4* __restrict__ Wsc,      // per-scan base, uint4 units
            const float* __restrict__ xin,
            float* __restrict__ hout,
            float* __restrict__ cbuf,           // [64][512] f32, carry between scans
            unsigned short* __restrict__ xb,    // [2][64][512] bf16 exchange
            unsigned int* __restrict__ ctr,     // [8] monotonic per batch-group
            int reverse, unsigned int step_base) {
  __shared__ uint4 Wl[8192];                    // 128 KiB  [kk][pl][j]
  __shared__ unsigned int cs_u[8 * 260];        // bf16-pair c, stride 260 (bank-spread)
  const int tid = threadIdx.x;
  const int bg = blockIdx.x & 7;
  const int dg = blockIdx.x >> 3;
  const int j = tid >> 3;                       // 0..63  (dim within group)
  const int bi = tid & 7;                       // 0..7   (batch within group)
  const int b = bg * 8 + bi;
  const int colbase = dg * 64 + j;
  // ---- preload weight slice into LDS (coalesced) ----
  const uint4* wsrc = Wsc + (size_t)dg * 8192;
#pragma unroll
  for (int w = 0; w < 16; ++w) Wl[tid + w * 512] = wsrc[tid + w * 512];
  // ---- preload full c (bf16 pairs) for my 8 batches ----
  {
    int bi2 = tid >> 6, p0 = (tid & 63) * 4;
    int bb = bg * 8 + bi2;
#pragma unroll
    for (int k2 = 0; k2 < 4; ++k2) {
      int p = p0 + k2;
      unsigned int lo = (unsigned int)f2bf(cbuf[bb * DD + 2 * p]);
      unsigned int hi = (unsigned int)f2bf(cbuf[bb * DD + 2 * p + 1]);
      cs_u[bi2 * 260 + p] = lo | (hi << 16);
    }
  }
  float c_reg = cbuf[b * DD + colbase];
  __syncthreads();

  unsigned int tgt = 8u * (step_base + 1u);
  for (int s = 0; s < LL; ++s, tgt += 8u) {
    const int t = reverse ? (LL - 1 - s) : s;
    const size_t rowg = (size_t)t * BB + b;
    float gi = bf2f(gx[rowg * NT + colbase]);
    float gf = bf2f(gx[rowg * NT + 512 + colbase]);
    float gc = bf2f(gx[rowg * NT + 1024 + colbase]);
    float xv = xin[rowg * DD + colbase];
    float a0 = 0.f, a1 = 0.f;
#pragma unroll 8
    for (int kk = 0; kk < 64; ++kk) {
      uint4 wa = Wl[kk * 128 + j];            // 8-way broadcast, conflict-free
      uint4 wb = Wl[kk * 128 + 64 + j];
      uint4 cp = *(const uint4*)&cs_u[bi * 260 + kk * 4];
      a0 = dot2bf(wa.x, cp.x, a0); a0 = dot2bf(wa.y, cp.y, a0);
      a0 = dot2bf(wa.z, cp.z, a0); a0 = dot2bf(wa.w, cp.w, a0);
      a1 = dot2bf(wb.x, cp.x, a1); a1 = dot2bf(wb.y, cp.y, a1);
      a1 = dot2bf(wb.z, cp.z, a1); a1 = dot2bf(wb.w, cp.w, a1);
    }
    float iv = 1.f / (1.f + __expf(-(gi + a0)));
    float fv = 1.f / (1.f + __expf(-(gf + a1)));
    float cn = fmaf(fv, c_reg, iv * gc);
    hout[rowg * DD + colbase] = tanhf(cn) + xv;
    c_reg = cn;
    // ---- publish my slice, sync batch-group, re-read full c ----
    xb[(size_t)(s & 1) * 32768 + b * DD + colbase] = f2bf(cn);
    __syncthreads();                           // drains all waves' stores (vmcnt)
    if (tid == 0) {
      __hip_atomic_fetch_add(&ctr[bg], 1u, __ATOMIC_RELEASE, __HIP_MEMORY_SCOPE_AGENT);
      while (__hip_atomic_load(&ctr[bg], __ATOMIC_ACQUIRE, __HIP_MEMORY_SCOPE_AGENT) < tgt)
        __builtin_amdgcn_s_sleep(2);
    }
    __syncthreads();
    {
      const unsigned long long* src =
          (const unsigned long long*)(xb + (size_t)(s & 1) * 32768);
      int bi2 = tid >> 6, p0 = (tid & 63) * 4;
      int bb = bg * 8 + bi2;
      int ui = bb * 256 + p0;
      unsigned long long v0 =
          __hip_atomic_load(&src[ui >> 1], __ATOMIC_RELAXED, __HIP_MEMORY_SCOPE_AGENT);
      unsigned long long v1 =
          __hip_atomic_load(&src[(ui >> 1) + 1], __ATOMIC_RELAXED, __HIP_MEMORY_SCOPE_AGENT);
      cs_u[bi2 * 260 + p0]     = (unsigned int)v0;
      cs_u[bi2 * 260 + p0 + 1] = (unsigned int)(v0 >> 32);
      cs_u[bi2 * 260 + p0 + 2] = (unsigned int)v1;
      cs_u[bi2 * 260 + p0 + 3] = (unsigned int)(v1 >> 32);
    }
    __syncthreads();
  }
  cbuf[b * DD + colbase] = c_reg;
}

extern "C" void kernel_launch(void* const* d_in, const int* in_sizes, int n_in,
                              void* d_out, int out_size, void* d_ws, size_t ws_size,
                              hipStream_t stream) {
  const int* xs = (const int*)d_in[0];
  const float* emb = (const float*)d_in[1];
  const float* Wx = (const float*)d_in[2];
  const float* Wc = (const float*)d_in[3];
  const float* bias = (const float*)d_in[4];
  float* out = (float*)d_out;
  char* ws = (char*)d_ws;

  unsigned short* gx = (unsigned short*)ws;                          // 96 MiB
  float* xB = (float*)(ws + (size_t)100663296);                      // 64 MiB
  unsigned int* Wp = (unsigned int*)(ws + (size_t)167772160);        // 4 MiB
  float* cbuf = (float*)(ws + (size_t)171966464);                    // 128 KiB
  unsigned short* xb = (unsigned short*)(ws + (size_t)172097536);    // 128 KiB
  unsigned int* ctr = (unsigned int*)(ws + (size_t)172228608);       // 32 B

  hipMemsetAsync(cbuf, 0, 131072, stream);
  hipMemsetAsync(ctr, 0, 32, stream);
  pack_wc_k<<<4096, 256, 0, stream>>>(Wc, Wp);
  gather_k<<<MROWS * 128 / 256, 256, 0, stream>>>(xs, emb, out);

  for (int s = 0; s < 4; ++s) {
    const float* xin = (s % 2 == 0) ? out : xB;
    float* xout = (s % 2 == 0) ? xB : out;
    gemm_k<<<dim3(NT / 128, MROWS / 128), 256, 0, stream>>>(
        xin, Wx + (size_t)s * DD * NT, bias + (size_t)s * NT, gx);
    scan_k<<<64, 512, 0, stream>>>(
        gx, (const uint4*)(Wp + (size_t)s * 262144), xin, xout, cbuf, xb, ctr,
        s & 1, (unsigned int)(s * 512));
  }
}

// Round 5
// 7328.561 us; speedup vs baseline: 4.9921x; 2.1856x over previous
//
#include <hip/hip_runtime.h>
#include <hip/hip_bf16.h>

#define DD 512
#define LL 512
#define BB 64
#define NT 1536
#define MROWS (LL*BB)

typedef short short8 __attribute__((ext_vector_type(8)));
typedef float floatx4 __attribute__((ext_vector_type(4)));
union U4S8 { uint4 u4; short8 s8; };

static __device__ __forceinline__ unsigned short f2bf(float f) {
  unsigned int u = __float_as_uint(f);
  unsigned int r = (u + 0x7fffu + ((u >> 16) & 1u)) >> 16;
  return (unsigned short)r;
}
static __device__ __forceinline__ float bf2f(unsigned short s) {
  return __uint_as_float(((unsigned int)s) << 16);
}

// Pack Wc[s][512 k][1024 col] f32 -> MFMA B-fragments, bf16 pairs.
// uint index (per scan,dg block of 32768): (((w*16 + ct*2+kt)*64 + lane)*4 + u)
// element k = w*64 + kt*32 + 8*(lane>>4) + 2u (+1 in high half)
// col_local = ct*16 + (lane&15); gcol = (cl>>6)*512 + dg*64 + (cl&63)
__global__ void pack_wc_k(const float* __restrict__ Wc, unsigned int* __restrict__ Wp) {
  int U = blockIdx.x * 256 + threadIdx.x;      // [0, 4*8*32768)
  int sdg = U >> 15;
  int s = sdg >> 3, dg = sdg & 7;
  int r = U & 32767;
  int u = r & 3;
  int lane = (r >> 2) & 63;
  int fidx = r >> 8;            // 0..127 = w*16 + ct*2 + kt
  int kt = fidx & 1;
  int ct = (fidx >> 1) & 7;
  int w = fidx >> 4;
  int k = w * 64 + kt * 32 + 8 * (lane >> 4) + 2 * u;
  int cl = ct * 16 + (lane & 15);
  int gcol = (cl >> 6) * 512 + dg * 64 + (cl & 63);
  size_t base = (size_t)s * DD * 1024;
  float lo = Wc[base + (size_t)k * 1024 + gcol];
  float hi = Wc[base + (size_t)(k + 1) * 1024 + gcol];
  Wp[U] = (unsigned int)f2bf(lo) | ((unsigned int)f2bf(hi) << 16);
}

__global__ void gather_k(const int* __restrict__ xs, const float* __restrict__ emb,
                         float* __restrict__ x) {
  int i = blockIdx.x * 256 + threadIdx.x;
  int row = i >> 7;
  int col = i & 127;
  const float4* src = (const float4*)(emb + (size_t)xs[row] * DD);
  ((float4*)(x + (size_t)row * DD))[col] = src[col];
}

// C[M,1536](bf16) = A[M,512] @ W[512,1536] + bias ; fp32 compute
__global__ __launch_bounds__(256)
void gemm_k(const float* __restrict__ A, const float* __restrict__ W,
            const float* __restrict__ bias, unsigned short* __restrict__ C) {
  __shared__ float As[16][128];
  __shared__ float Bs[16][128];
  const int tid = threadIdx.x;
  const int tx = tid & 15;
  const int ty = tid >> 4;
  const int m0 = blockIdx.y * 128;
  const int n0 = blockIdx.x * 128;
  const int lm = tid >> 1;
  const int lk = (tid & 1) * 8;
  const int wk = tid >> 4;
  const int wn = (tid & 15) * 8;
  float acc[8][8];
#pragma unroll
  for (int i = 0; i < 8; ++i)
#pragma unroll
    for (int j = 0; j < 8; ++j) acc[i][j] = 0.f;

  for (int k0 = 0; k0 < DD; k0 += 16) {
    float4 a0 = *(const float4*)(A + (size_t)(m0 + lm) * DD + k0 + lk);
    float4 a1 = *(const float4*)(A + (size_t)(m0 + lm) * DD + k0 + lk + 4);
    float4 w0 = *(const float4*)(W + (size_t)(k0 + wk) * NT + n0 + wn);
    float4 w1 = *(const float4*)(W + (size_t)(k0 + wk) * NT + n0 + wn + 4);
    __syncthreads();
    As[lk + 0][lm] = a0.x; As[lk + 1][lm] = a0.y; As[lk + 2][lm] = a0.z; As[lk + 3][lm] = a0.w;
    As[lk + 4][lm] = a1.x; As[lk + 5][lm] = a1.y; As[lk + 6][lm] = a1.z; As[lk + 7][lm] = a1.w;
    *(float4*)&Bs[wk][wn] = w0;
    *(float4*)&Bs[wk][wn + 4] = w1;
    __syncthreads();
#pragma unroll
    for (int kk = 0; kk < 16; ++kk) {
      float a[8], w[8];
      *(float4*)&a[0] = *(const float4*)&As[kk][ty * 8];
      *(float4*)&a[4] = *(const float4*)&As[kk][ty * 8 + 4];
      *(float4*)&w[0] = *(const float4*)&Bs[kk][tx * 8];
      *(float4*)&w[4] = *(const float4*)&Bs[kk][tx * 8 + 4];
#pragma unroll
      for (int i = 0; i < 8; ++i)
#pragma unroll
        for (int j = 0; j < 8; ++j)
          acc[i][j] = fmaf(a[i], w[j], acc[i][j]);
    }
  }
#pragma unroll
  for (int i = 0; i < 8; ++i) {
    size_t rb = (size_t)(m0 + ty * 8 + i) * NT + n0 + tx * 8;
#pragma unroll
    for (int jv = 0; jv < 2; ++jv) {
      ushort4 v;
      v.x = f2bf(acc[i][jv*4+0] + bias[n0 + tx*8 + jv*4 + 0]);
      v.y = f2bf(acc[i][jv*4+1] + bias[n0 + tx*8 + jv*4 + 1]);
      v.z = f2bf(acc[i][jv*4+2] + bias[n0 + tx*8 + jv*4 + 2]);
      v.w = f2bf(acc[i][jv*4+3] + bias[n0 + tx*8 + jv*4 + 3]);
      *(ushort4*)(C + rb + jv*4) = v;
    }
  }
}

// 64 blocks = 8 batch-groups x 8 dim-groups. Weights register-resident as
// MFMA B-frags (wave w owns K-slice [w*64,w*64+64)). c exchanged per step via
// relaxed agent atomics (write-through coherent, no wbl2/inv) + per-slot flags.
__global__ __launch_bounds__(512, 2)
void scan_k(const unsigned short* __restrict__ gx,
            const uint4* __restrict__ Wsc,      // per-scan base, uint4 units
            const float* __restrict__ xin,
            float* __restrict__ hout,
            float* __restrict__ cbuf,           // [64][512] f32
            unsigned int* __restrict__ xbw,     // [2][64][256] u32 (bf16-pair c)
            unsigned int* __restrict__ flags,   // [8 bg][8 dg] monotonic
            int reverse, unsigned int step_base) {
  __shared__ __align__(16) unsigned int cs_u[8 * 260];   // bf16-pair c, padded rows
  __shared__ float pd[8 * 8 * 128];                      // per-wave partials
  const int tid = threadIdx.x;
  const int bg = blockIdx.x & 7;
  const int dg = blockIdx.x >> 3;
  const int lane = tid & 63;
  const int w = tid >> 6;           // wave 0..7 (= K-slice owner)
  const int b = tid >> 6;           // batch-in-group for gate phase
  const int d = tid & 63;           // dim-in-group for gate phase
  const int batch = bg * 8 + b;
  const int dim = dg * 64 + d;

  // ---- weights -> registers (16 B-frags per lane, 64 VGPR) ----
  uint4 Wf[16];
  {
    const uint4* ws = Wsc + (size_t)dg * 8192;
#pragma unroll
    for (int f = 0; f < 16; ++f)
      Wf[f] = ws[(size_t)(w * 16 + f) * 64 + lane];
  }
  // ---- init cs from cbuf (bf16 pairs) ----
  {
    int bi2 = tid >> 6, p0 = (tid & 63) * 4;
    int bb = bg * 8 + bi2;
#pragma unroll
    for (int k2 = 0; k2 < 4; ++k2) {
      int p = p0 + k2;
      unsigned int lo = (unsigned int)f2bf(cbuf[bb * DD + 2 * p]);
      unsigned int hi = (unsigned int)f2bf(cbuf[bb * DD + 2 * p + 1]);
      cs_u[bi2 * 260 + p] = lo | (hi << 16);
    }
  }
  float c_reg = cbuf[batch * DD + dim];
  // ---- prologue prefetch (step 0) ----
  {
    int t0 = reverse ? (LL - 1) : 0;
    size_t rg = (size_t)t0 * BB + batch;
    (void)rg;
  }
  int t0 = reverse ? (LL - 1) : 0;
  size_t rg0 = (size_t)t0 * BB + batch;
  float g_i = bf2f(gx[rg0 * NT + dim]);
  float g_f = bf2f(gx[rg0 * NT + 512 + dim]);
  float g_c = bf2f(gx[rg0 * NT + 1024 + dim]);
  float x_v = xin[rg0 * DD + dim];
  __syncthreads();

  for (int s = 0; s < LL; ++s) {
    // ---- (A) MFMA partial gcarry over this wave's K-slice ----
    {
      const int arow = lane & 7;
      U4S8 a0, a1;
      a0.u4 = *(const uint4*)&cs_u[arow * 260 + w * 32 + 4 * (lane >> 4)];
      a1.u4 = *(const uint4*)&cs_u[arow * 260 + w * 32 + 16 + 4 * (lane >> 4)];
#pragma unroll
      for (int ct = 0; ct < 8; ++ct) {
        U4S8 b0, b1;
        b0.u4 = Wf[ct * 2];
        b1.u4 = Wf[ct * 2 + 1];
        floatx4 acc = __builtin_amdgcn_mfma_f32_16x16x32_bf16(
            a0.s8, b0.s8, (floatx4){0.f, 0.f, 0.f, 0.f}, 0, 0, 0);
        acc = __builtin_amdgcn_mfma_f32_16x16x32_bf16(a1.s8, b1.s8, acc, 0, 0, 0);
        if (lane < 32) {
          int colb = ct * 16 + (lane & 15);
          int rb = (lane >> 4) * 4;
#pragma unroll
          for (int e = 0; e < 4; ++e)
            pd[(w * 8 + rb + e) * 128 + colb] = acc[e];
        }
      }
    }
    __syncthreads();                                   // (B) partials ready
    // ---- (C) reduce partials + gates + publish ----
    float gsi = 0.f, gsf = 0.f;
#pragma unroll
    for (int ww = 0; ww < 8; ++ww) {
      gsi += pd[(ww * 8 + b) * 128 + d];
      gsf += pd[(ww * 8 + b) * 128 + 64 + d];
    }
    float iv = 1.f / (1.f + __expf(-(g_i + gsi)));
    float fv = 1.f / (1.f + __expf(-(g_f + gsf)));
    float cn = fmaf(fv, c_reg, iv * g_c);
    const int t = reverse ? (LL - 1 - s) : s;
    size_t rowg = (size_t)t * BB + batch;
    hout[rowg * DD + dim] = tanhf(cn) + x_v;
    c_reg = cn;
    {   // prefetch next step's gx/xin (overlaps exchange latency)
      int tn = (s + 1 < LL) ? (reverse ? (LL - 2 - s) : (s + 1)) : t;
      size_t rn = (size_t)tn * BB + batch;
      g_i = bf2f(gx[rn * NT + dim]);
      g_f = bf2f(gx[rn * NT + 512 + dim]);
      g_c = bf2f(gx[rn * NT + 1024 + dim]);
      x_v = xin[rn * DD + dim];
    }
    unsigned int vb = (unsigned int)f2bf(cn);
    unsigned int ob = (unsigned int)__shfl_down((int)vb, 1);
    if ((d & 1) == 0) {
      unsigned int* dst = xbw + (size_t)(s & 1) * 16384 + batch * 256 + dg * 32 + (d >> 1);
      __hip_atomic_store(dst, vb | (ob << 16), __ATOMIC_RELAXED, __HIP_MEMORY_SCOPE_AGENT);
    }
    __syncthreads();                                   // (D) publish drained (vmcnt 0)
    unsigned int tgt = step_base + (unsigned int)s + 1u;
    if (tid == 0) {
      __hip_atomic_store(&flags[bg * 8 + dg], tgt, __ATOMIC_RELAXED, __HIP_MEMORY_SCOPE_AGENT);
      const unsigned long long* fl = (const unsigned long long*)(flags + bg * 8);
      for (;;) {
        unsigned long long f0 = __hip_atomic_load(&fl[0], __ATOMIC_RELAXED, __HIP_MEMORY_SCOPE_AGENT);
        unsigned long long f1 = __hip_atomic_load(&fl[1], __ATOMIC_RELAXED, __HIP_MEMORY_SCOPE_AGENT);
        unsigned long long f2 = __hip_atomic_load(&fl[2], __ATOMIC_RELAXED, __HIP_MEMORY_SCOPE_AGENT);
        unsigned long long f3 = __hip_atomic_load(&fl[3], __ATOMIC_RELAXED, __HIP_MEMORY_SCOPE_AGENT);
        unsigned int m0 = min(min((unsigned int)f0, (unsigned int)(f0 >> 32)),
                              min((unsigned int)f1, (unsigned int)(f1 >> 32)));
        unsigned int m1 = min(min((unsigned int)f2, (unsigned int)(f2 >> 32)),
                              min((unsigned int)f3, (unsigned int)(f3 >> 32)));
        if (min(m0, m1) >= tgt) break;
        __builtin_amdgcn_s_sleep(1);
      }
    }
    __syncthreads();                                   // (F) all slices published
    // ---- (G) reload full c for my 8 batches ----
    {
      const unsigned long long* src =
          (const unsigned long long*)(xbw + (size_t)(s & 1) * 16384) + bg * 1024;
#pragma unroll
      for (int h = 0; h < 2; ++h) {
        int q = tid + h * 512;
        unsigned long long v =
            __hip_atomic_load(&src[q], __ATOMIC_RELAXED, __HIP_MEMORY_SCOPE_AGENT);
        int wi = q * 2;
        int bi2 = wi >> 8, p = wi & 255;
        cs_u[bi2 * 260 + p] = (unsigned int)v;
        cs_u[bi2 * 260 + p + 1] = (unsigned int)(v >> 32);
      }
    }
    __syncthreads();                                   // (H) cs ready
  }
  cbuf[batch * DD + dim] = c_reg;
}

extern "C" void kernel_launch(void* const* d_in, const int* in_sizes, int n_in,
                              void* d_out, int out_size, void* d_ws, size_t ws_size,
                              hipStream_t stream) {
  const int* xs = (const int*)d_in[0];
  const float* emb = (const float*)d_in[1];
  const float* Wx = (const float*)d_in[2];
  const float* Wc = (const float*)d_in[3];
  const float* bias = (const float*)d_in[4];
  float* out = (float*)d_out;
  char* ws = (char*)d_ws;

  unsigned short* gx = (unsigned short*)ws;                          // 96 MiB
  float* xB = (float*)(ws + (size_t)100663296);                      // 64 MiB
  unsigned int* Wp = (unsigned int*)(ws + (size_t)167772160);        // 4 MiB
  float* cbuf = (float*)(ws + (size_t)171966464);                    // 128 KiB
  unsigned int* xbw = (unsigned int*)(ws + (size_t)172097536);       // 128 KiB
  unsigned int* flags = (unsigned int*)(ws + (size_t)172228608);     // 256 B

  hipMemsetAsync(cbuf, 0, 131072, stream);
  hipMemsetAsync(flags, 0, 256, stream);
  pack_wc_k<<<4096, 256, 0, stream>>>(Wc, Wp);
  gather_k<<<MROWS * 128 / 256, 256, 0, stream>>>(xs, emb, out);

  for (int s = 0; s < 4; ++s) {
    const float* xin = (s % 2 == 0) ? out : xB;
    float* xout = (s % 2 == 0) ? xB : out;
    gemm_k<<<dim3(NT / 128, MROWS / 128), 256, 0, stream>>>(
        xin, Wx + (size_t)s * DD * NT, bias + (size_t)s * NT, gx);
    scan_k<<<64, 512, 0, stream>>>(
        gx, (const uint4*)(Wp + (size_t)s * 262144), xin, xout, cbuf, xbw, flags,
        s & 1, (unsigned int)(s * 512));
  }
}

// Round 7
// 5847.001 us; speedup vs baseline: 6.2570x; 1.2534x over previous
//
#include <hip/hip_runtime.h>
#include <hip/hip_bf16.h>

#define DD 512
#define LL 512
#define BB 64
#define NT 1536
#define MROWS (LL*BB)

typedef short short8 __attribute__((ext_vector_type(8)));
typedef float floatx4 __attribute__((ext_vector_type(4)));
union U4S8 { uint4 u4; short8 s8; };
typedef unsigned long long ull;

static __device__ __forceinline__ unsigned short f2bf(float f) {
  unsigned int u = __float_as_uint(f);
  unsigned int r = (u + 0x7fffu + ((u >> 16) & 1u)) >> 16;
  return (unsigned short)r;
}
static __device__ __forceinline__ float bf2f(unsigned short s) {
  return __uint_as_float(((unsigned int)s) << 16);
}

// Pack Wc[s][512 k][1024 col] f32 -> MFMA B-fragments, bf16 pairs (round-5 proven layout).
__global__ void pack_wc_k(const float* __restrict__ Wc, unsigned int* __restrict__ Wp) {
  int U = blockIdx.x * 256 + threadIdx.x;      // [0, 4*8*32768)
  int sdg = U >> 15;
  int s = sdg >> 3, dg = sdg & 7;
  int r = U & 32767;
  int u = r & 3;
  int lane = (r >> 2) & 63;
  int fidx = r >> 8;            // 0..127 = w*16 + ct*2 + kt
  int kt = fidx & 1;
  int ct = (fidx >> 1) & 7;
  int w = fidx >> 4;
  int k = w * 64 + kt * 32 + 8 * (lane >> 4) + 2 * u;
  int cl = ct * 16 + (lane & 15);
  int gcol = (cl >> 6) * 512 + dg * 64 + (cl & 63);
  size_t base = (size_t)s * DD * 1024;
  float lo = Wc[base + (size_t)k * 1024 + gcol];
  float hi = Wc[base + (size_t)(k + 1) * 1024 + gcol];
  Wp[U] = (unsigned int)f2bf(lo) | ((unsigned int)f2bf(hi) << 16);
}

// Transpose Wx[s][512 k][1536 n] f32 -> Wxp[s][1536 n][512 k] bf16 (tiled).
__global__ __launch_bounds__(256)
void pack_wx_k(const float* __restrict__ W, unsigned short* __restrict__ Wxp) {
  __shared__ float t[64][65];
  int k0 = blockIdx.x * 64, n0 = blockIdx.y * 64, s = blockIdx.z;
  int tx = threadIdx.x & 63, ty = threadIdx.x >> 6;
  const float* Wb = W + (size_t)s * DD * NT;
#pragma unroll
  for (int i = 0; i < 16; ++i) {
    int k = ty * 16 + i;
    t[k][tx] = Wb[(size_t)(k0 + k) * NT + n0 + tx];
  }
  __syncthreads();
  unsigned short* Ob = Wxp + (size_t)s * NT * DD;
#pragma unroll
  for (int i = 0; i < 16; ++i) {
    int n = ty * 16 + i;
    Ob[(size_t)(n0 + n) * DD + k0 + tx] = f2bf(t[tx][n]);
  }
}

__global__ void gather_k(const int* __restrict__ xs, const float* __restrict__ emb,
                         float* __restrict__ x) {
  int i = blockIdx.x * 256 + threadIdx.x;
  int row = i >> 7;
  int col = i & 127;
  const float4* src = (const float4*)(emb + (size_t)xs[row] * DD);
  ((float4*)(x + (size_t)row * DD))[col] = src[col];
}

// ---------------- fallback fp32 GEMM (proven) ----------------
__global__ __launch_bounds__(256)
void gemm_k(const float* __restrict__ A, const float* __restrict__ W,
            const float* __restrict__ bias, unsigned short* __restrict__ C) {
  __shared__ float As[16][128];
  __shared__ float Bs[16][128];
  const int tid = threadIdx.x;
  const int tx = tid & 15;
  const int ty = tid >> 4;
  const int m0 = blockIdx.y * 128;
  const int n0 = blockIdx.x * 128;
  const int lm = tid >> 1;
  const int lk = (tid & 1) * 8;
  const int wk = tid >> 4;
  const int wn = (tid & 15) * 8;
  float acc[8][8];
#pragma unroll
  for (int i = 0; i < 8; ++i)
#pragma unroll
    for (int j = 0; j < 8; ++j) acc[i][j] = 0.f;
  for (int k0 = 0; k0 < DD; k0 += 16) {
    float4 a0 = *(const float4*)(A + (size_t)(m0 + lm) * DD + k0 + lk);
    float4 a1 = *(const float4*)(A + (size_t)(m0 + lm) * DD + k0 + lk + 4);
    float4 w0 = *(const float4*)(W + (size_t)(k0 + wk) * NT + n0 + wn);
    float4 w1 = *(const float4*)(W + (size_t)(k0 + wk) * NT + n0 + wn + 4);
    __syncthreads();
    As[lk + 0][lm] = a0.x; As[lk + 1][lm] = a0.y; As[lk + 2][lm] = a0.z; As[lk + 3][lm] = a0.w;
    As[lk + 4][lm] = a1.x; As[lk + 5][lm] = a1.y; As[lk + 6][lm] = a1.z; As[lk + 7][lm] = a1.w;
    *(float4*)&Bs[wk][wn] = w0;
    *(float4*)&Bs[wk][wn + 4] = w1;
    __syncthreads();
#pragma unroll
    for (int kk = 0; kk < 16; ++kk) {
      float a[8], w[8];
      *(float4*)&a[0] = *(const float4*)&As[kk][ty * 8];
      *(float4*)&a[4] = *(const float4*)&As[kk][ty * 8 + 4];
      *(float4*)&w[0] = *(const float4*)&Bs[kk][tx * 8];
      *(float4*)&w[4] = *(const float4*)&Bs[kk][tx * 8 + 4];
#pragma unroll
      for (int i = 0; i < 8; ++i)
#pragma unroll
        for (int j = 0; j < 8; ++j)
          acc[i][j] = fmaf(a[i], w[j], acc[i][j]);
    }
  }
#pragma unroll
  for (int i = 0; i < 8; ++i) {
    size_t rb = (size_t)(m0 + ty * 8 + i) * NT + n0 + tx * 8;
#pragma unroll
    for (int jv = 0; jv < 2; ++jv) {
      ushort4 v;
      v.x = f2bf(acc[i][jv*4+0] + bias[n0 + tx*8 + jv*4 + 0]);
      v.y = f2bf(acc[i][jv*4+1] + bias[n0 + tx*8 + jv*4 + 1]);
      v.z = f2bf(acc[i][jv*4+2] + bias[n0 + tx*8 + jv*4 + 2]);
      v.w = f2bf(acc[i][jv*4+3] + bias[n0 + tx*8 + jv*4 + 3]);
      *(ushort4*)(C + rb + jv*4) = v;
    }
  }
}

// ---------------- bf16 MFMA GEMM: C[M,1536](bf16) = A_f32[M,512] @ Wt[1536,512]^T + bias
// 128x128 tile, 256 threads = 4 waves (2x2), each wave 64x64 via 4x4 16x16x32 frags.
__global__ __launch_bounds__(256)
void gemm_m_k(const float* __restrict__ A, const unsigned short* __restrict__ Wt,
              const float* __restrict__ bias, unsigned short* __restrict__ C) {
  __shared__ unsigned short Al[128 * 40];    // row stride 40 ushorts (80B) kills conflicts
  __shared__ unsigned short Bl[128 * 40];
  const int tid = threadIdx.x;
  const int m0 = blockIdx.y * 128, n0 = blockIdx.x * 128;
  const int wave = tid >> 6, lane = tid & 63;
  const int wm = wave >> 1, wn = wave & 1;
  const int l15 = lane & 15, lh = lane >> 4;
  floatx4 acc[4][4];
#pragma unroll
  for (int i = 0; i < 4; ++i)
#pragma unroll
    for (int j = 0; j < 4; ++j) acc[i][j] = (floatx4){0.f, 0.f, 0.f, 0.f};

  const int ar = tid >> 3, ac = (tid & 7) * 4;       // A: 32 rows/pass x 8 thr
  const int br = tid >> 2, bc = (tid & 3) * 8;       // B: 64 rows/pass x 4 thr
#pragma unroll 1
  for (int k0 = 0; k0 < DD; k0 += 32) {
    float4 av[4];
#pragma unroll
    for (int p = 0; p < 4; ++p)
      av[p] = *(const float4*)(A + (size_t)(m0 + ar + p * 32) * DD + k0 + ac);
    uint4 bv0 = *(const uint4*)(Wt + (size_t)(n0 + br) * DD + k0 + bc);
    uint4 bv1 = *(const uint4*)(Wt + (size_t)(n0 + br + 64) * DD + k0 + bc);
    __syncthreads();
#pragma unroll
    for (int p = 0; p < 4; ++p) {
      ushort4 w4;
      w4.x = f2bf(av[p].x); w4.y = f2bf(av[p].y);
      w4.z = f2bf(av[p].z); w4.w = f2bf(av[p].w);
      *(ushort4*)&Al[(ar + p * 32) * 40 + ac] = w4;
    }
    *(uint4*)&Bl[br * 40 + bc] = bv0;
    *(uint4*)&Bl[(br + 64) * 40 + bc] = bv1;
    __syncthreads();
    U4S8 af[4], bf[4];
#pragma unroll
    for (int mf = 0; mf < 4; ++mf)
      af[mf].u4 = *(const uint4*)&Al[(wm * 64 + mf * 16 + l15) * 40 + lh * 8];
#pragma unroll
    for (int nf = 0; nf < 4; ++nf)
      bf[nf].u4 = *(const uint4*)&Bl[(wn * 64 + nf * 16 + l15) * 40 + lh * 8];
#pragma unroll
    for (int mf = 0; mf < 4; ++mf)
#pragma unroll
      for (int nf = 0; nf < 4; ++nf)
        acc[mf][nf] = __builtin_amdgcn_mfma_f32_16x16x32_bf16(
            af[mf].s8, bf[nf].s8, acc[mf][nf], 0, 0, 0);
  }
#pragma unroll
  for (int nf = 0; nf < 4; ++nf) {
    int n = n0 + wn * 64 + nf * 16 + l15;
    float bn = bias[n];
#pragma unroll
    for (int mf = 0; mf < 4; ++mf) {
      int row = m0 + wm * 64 + mf * 16 + lh * 4;
      size_t base = (size_t)row * NT + n;
#pragma unroll
      for (int e = 0; e < 4; ++e)
        C[base + (size_t)e * NT] = f2bf(acc[mf][nf][e] + bn);
    }
  }
}

// ---------------- scan: 64 blocks = 8 bg x 8 dg; weights register-resident; c via
// relaxed agent atomics; per-wave flag gating (flags store-only, set after barrier).
__global__ __launch_bounds__(512, 1)
void scan_k(const unsigned short* __restrict__ gx,
            const uint4* __restrict__ Wsc,
            const float* __restrict__ xin,
            float* __restrict__ hout,
            float* __restrict__ cbuf,           // [64][512] f32
            unsigned short* __restrict__ xbu,   // [2][64][512] bf16
            unsigned int* __restrict__ flags,   // [8 bg][8 dg] monotonic
            int reverse, unsigned int step_base) {
  __shared__ float pd[8192];                    // 32 KiB partials
  const int tid = threadIdx.x;
  const int bg = blockIdx.x & 7;
  const int dg = blockIdx.x >> 3;
  const int lane = tid & 63;
  const int w = tid >> 6;
  const int batch = bg * 8 + w;
  const int dim = dg * 64 + lane;

  uint4 Wf[16];
  {
    const uint4* ws = Wsc + (size_t)dg * 8192;
#pragma unroll
    for (int f = 0; f < 16; ++f)
      Wf[f] = ws[(size_t)(w * 16 + f) * 64 + lane];
  }
  float c_reg = cbuf[batch * DD + dim];
  int t0 = reverse ? (LL - 1) : 0;
  size_t r0 = (size_t)t0 * BB + batch;
  float g_i = bf2f(gx[r0 * NT + dim]);
  float g_f = bf2f(gx[r0 * NT + 512 + dim]);
  float g_c = bf2f(gx[r0 * NT + 1024 + dim]);
  float x_v = xin[r0 * DD + dim];
  const int arow = lane & 7, lh = lane >> 4;

#pragma unroll 1
  for (int s = 0; s < LL; ++s) {
    unsigned int need = step_base + (unsigned int)s;
    // ---- per-wave gate: partner block (bg, w) has published step s-1 ----
    {
      const unsigned int* f = flags + bg * 8 + w;
      while (__hip_atomic_load(f, __ATOMIC_RELAXED, __HIP_MEMORY_SCOPE_AGENT) < need)
        __builtin_amdgcn_s_sleep(1);
    }
    // ---- A-frags direct from exchange buffer, parity (s+1)&1 ----
    const ull* src = (const ull*)xbu + (size_t)(((s + 1) & 1)) * 8192;
    int ai = (bg * 8 + arow) * 128 + w * 16 + 2 * lh;
    ull v0 = __hip_atomic_load(&src[ai],     __ATOMIC_RELAXED, __HIP_MEMORY_SCOPE_AGENT);
    ull v1 = __hip_atomic_load(&src[ai + 1], __ATOMIC_RELAXED, __HIP_MEMORY_SCOPE_AGENT);
    ull v2 = __hip_atomic_load(&src[ai + 8], __ATOMIC_RELAXED, __HIP_MEMORY_SCOPE_AGENT);
    ull v3 = __hip_atomic_load(&src[ai + 9], __ATOMIC_RELAXED, __HIP_MEMORY_SCOPE_AGENT);
    // ---- prefetch next step's gx/xin (consumed after the barrier) ----
    int sn = (s + 1 < LL) ? s + 1 : s;
    int tn = reverse ? (LL - 1 - sn) : sn;
    size_t rn = (size_t)tn * BB + batch;
    float ngi = bf2f(gx[rn * NT + dim]);
    float ngf = bf2f(gx[rn * NT + 512 + dim]);
    float ngc = bf2f(gx[rn * NT + 1024 + dim]);
    float nxv = xin[rn * DD + dim];
    // ---- MFMA partials over this wave's K-slice ----
    U4S8 A0, A1;
    A0.u4 = make_uint4((unsigned int)v0, (unsigned int)(v0 >> 32),
                       (unsigned int)v1, (unsigned int)(v1 >> 32));
    A1.u4 = make_uint4((unsigned int)v2, (unsigned int)(v2 >> 32),
                       (unsigned int)v3, (unsigned int)(v3 >> 32));
#pragma unroll
    for (int ct = 0; ct < 8; ++ct) {
      U4S8 B0, B1; B0.u4 = Wf[ct * 2]; B1.u4 = Wf[ct * 2 + 1];
      floatx4 acc = __builtin_amdgcn_mfma_f32_16x16x32_bf16(
          A0.s8, B0.s8, (floatx4){0.f, 0.f, 0.f, 0.f}, 0, 0, 0);
      acc = __builtin_amdgcn_mfma_f32_16x16x32_bf16(A1.s8, B1.s8, acc, 0, 0, 0);
      if (lane < 32) {
        int colb = ct * 16 + (lane & 15);
        int rb = (lane >> 4) * 4;
#pragma unroll
        for (int e = 0; e < 4; ++e)
          pd[(w * 8 + rb + e) * 128 + colb] = acc[e];
      }
    }
    __syncthreads();
    // ---- reduce + gates (wave w owns batch bg*8+w, dim = dg*64+lane) ----
    float gsi = 0.f, gsf = 0.f;
#pragma unroll
    for (int ww = 0; ww < 8; ++ww) {
      gsi += pd[(ww * 8 + w) * 128 + lane];
      gsf += pd[(ww * 8 + w) * 128 + 64 + lane];
    }
    float iv = 1.f / (1.f + __expf(-(g_i + gsi)));
    float fv = 1.f / (1.f + __expf(-(g_f + gsf)));
    float cn = fmaf(fv, c_reg, iv * g_c);
    c_reg = cn;
    // ---- publish (2B relaxed agent store; 128B contiguous per wave) ----
    __hip_atomic_store(xbu + (size_t)((s & 1)) * 32768 + batch * DD + dim,
                       f2bf(cn), __ATOMIC_RELAXED, __HIP_MEMORY_SCOPE_AGENT);
    // ---- off-critical tail ----
    int t = reverse ? (LL - 1 - s) : s;
    size_t rowg = (size_t)t * BB + batch;
    hout[rowg * DD + dim] = tanhf(cn) + x_v;
    g_i = ngi; g_f = ngf; g_c = ngc; x_v = nxv;
    __syncthreads();   // vmcnt(0) drain: all waves' publishes device-visible
    if (tid == 0)
      __hip_atomic_store(&flags[bg * 8 + dg], need + 1u,
                         __ATOMIC_RELAXED, __HIP_MEMORY_SCOPE_AGENT);
  }
  cbuf[batch * DD + dim] = c_reg;
}

extern "C" void kernel_launch(void* const* d_in, const int* in_sizes, int n_in,
                              void* d_out, int out_size, void* d_ws, size_t ws_size,
                              hipStream_t stream) {
  const int* xs = (const int*)d_in[0];
  const float* emb = (const float*)d_in[1];
  const float* Wx = (const float*)d_in[2];
  const float* Wc = (const float*)d_in[3];
  const float* bias = (const float*)d_in[4];
  float* out = (float*)d_out;
  char* ws = (char*)d_ws;

  unsigned short* gx = (unsigned short*)ws;                          // 96 MiB
  float* xB = (float*)(ws + (size_t)100663296);                      // 64 MiB
  unsigned int* Wp = (unsigned int*)(ws + (size_t)167772160);        // 4 MiB
  float* cbuf = (float*)(ws + (size_t)171966464);                    // 128 KiB
  unsigned short* xbu = (unsigned short*)(ws + (size_t)172097536);   // 128 KiB
  unsigned int* flags = (unsigned int*)(ws + (size_t)172228608);     // 256 B
  unsigned short* Wxp = (unsigned short*)(ws + (size_t)172229632);   // 6 MiB
  const size_t NEED = 178521088ull;
  const bool use_mfma_gemm = (ws_size >= NEED);

  hipMemsetAsync(cbuf, 0, 131072, stream);
  hipMemsetAsync(xbu, 0, 131072, stream);    // seed parity-1 with bf16(c0)=0
  hipMemsetAsync(flags, 0, 256, stream);
  pack_wc_k<<<4096, 256, 0, stream>>>(Wc, Wp);
  if (use_mfma_gemm)
    pack_wx_k<<<dim3(8, 24, 4), 256, 0, stream>>>(Wx, Wxp);
  gather_k<<<MROWS * 128 / 256, 256, 0, stream>>>(xs, emb, out);

  for (int s = 0; s < 4; ++s) {
    const float* xin = (s % 2 == 0) ? out : xB;
    float* xout = (s % 2 == 0) ? xB : out;
    if (use_mfma_gemm)
      gemm_m_k<<<dim3(NT / 128, MROWS / 128), 256, 0, stream>>>(
          xin, Wxp + (size_t)s * NT * DD, bias + (size_t)s * NT, gx);
    else
      gemm_k<<<dim3(NT / 128, MROWS / 128), 256, 0, stream>>>(
          xin, Wx + (size_t)s * DD * NT, bias + (size_t)s * NT, gx);
    scan_k<<<64, 512, 0, stream>>>(
        gx, (const uint4*)(Wp + (size_t)s * 262144), xin, xout, cbuf, xbu, flags,
        s & 1, (unsigned int)(s * 512));
  }
}